// Round 1
// baseline (9009.226 us; speedup 1.0000x reference)
//
#include <hip/hip_runtime.h>
#include <cstdint>
#include <cstddef>

// Flip to 0 if zq absmax comes back O(1-8): that is the "wrong PRNG layout"
// signature -> fall back to legacy (pre-partitionable) JAX threefry semantics.
#define JAX_PARTITIONABLE 1

namespace {

constexpr int Bsz = 16, Nn = 1024, Dd = 256, Kk = 16, Ss = 512;
constexpr uint32_t BN = (uint32_t)Bsz * Nn;                    // 16384
constexpr uint32_t BNKS = (uint32_t)Bsz * Nn * Kk * Ss;        // 134217728
constexpr int ZQ_SIZE = Bsz * Nn * Dd;                          // 4194304
constexpr int PQ_OFF = ZQ_SIZE;
constexpr int PROB_OFF = ZQ_SIZE + 1;
constexpr int BNS = Bsz * Nn * Ss;                              // 8388608
constexpr int LP_OFF = PROB_OFF + BNS;

// workspace layout (float offsets)
constexpr int WS_CP = 0;                         // 256
constexpr int WS_Z2 = 256;                       // 16384
constexpr int WS_B2 = WS_Z2 + (int)BN;           // 8192
constexpr int WS_WB2 = WS_B2 + Kk * Ss;          // 8192
constexpr int WS_WBOOKS = WS_WB2 + Bsz * Ss;     // B*S*D = 2097152
// total ~8.5 MB

struct KP { uint32_t a, b; };

__host__ __device__ constexpr KP tf2x32(uint32_t k0, uint32_t k1,
                                        uint32_t x0, uint32_t x1) {
  uint32_t ks0 = k0, ks1 = k1, ks2 = k0 ^ k1 ^ 0x1BD11BDAu;
  uint32_t ks[3] = {ks0, ks1, ks2};
  const int rot[2][4] = {{13, 15, 26, 6}, {17, 29, 16, 24}};
  x0 += ks[0];
  x1 += ks[1];
#pragma unroll
  for (int i = 0; i < 5; ++i) {
#pragma unroll
    for (int j = 0; j < 4; ++j) {
      int r = rot[i & 1][j];
      x0 += x1;
      x1 = (x1 << r) | (x1 >> (32 - r));
      x1 ^= x0;
    }
    x0 += ks[(i + 1) % 3];
    x1 += ks[(i + 2) % 3] + (uint32_t)(i + 1);
  }
  return {x0, x1};
}

// gkey = jax.random.key(42) = (0,42); kg1, kg2 = split(gkey)
#if JAX_PARTITIONABLE
constexpr KP KG1 = tf2x32(0u, 42u, 0u, 0u);
constexpr KP KG2 = tf2x32(0u, 42u, 0u, 1u);
#else
constexpr KP KH0 = tf2x32(0u, 42u, 0u, 2u);
constexpr KP KH1 = tf2x32(0u, 42u, 1u, 3u);
constexpr KP KG1 = {KH0.a, KH1.a};
constexpr KP KG2 = {KH0.b, KH1.b};
#endif

__device__ __forceinline__ float jax_gumbel(KP key, uint32_t idx, uint32_t half) {
#if JAX_PARTITIONABLE
  KP h = tf2x32(key.a, key.b, 0u, idx);
  uint32_t bits = h.a ^ h.b;
#else
  uint32_t lo = idx < half ? idx : idx - half;
  KP h = tf2x32(key.a, key.b, lo, lo + half);
  uint32_t bits = idx < half ? h.a : h.b;
#endif
  float u = __uint_as_float((bits >> 9) | 0x3F800000u) - 1.0f;
  return -__logf(-__logf(u + 1e-10f) + 1e-10f);
}

__device__ __forceinline__ float prec_q(const float* p) {
  return 0.5f / fmaxf(1.0f + expf(p[0]), 1e-10f);
}

// ---------------- K1: c_probs (B,K) + precision_q ----------------
__global__ void __launch_bounds__(256) cprobs_kernel(
    const float* __restrict__ c_logits, const float* __restrict__ lpq,
    const float* __restrict__ lpq_cls, float* __restrict__ ws,
    float* __restrict__ out) {
  __shared__ float sl[256];
  const int t = threadIdx.x;
  const float pqc = prec_q(lpq_cls);
  float g = jax_gumbel(KG1, (uint32_t)t, 128u);
  sl[t] = (c_logits[t] * pqc + g) * 2.0f;  // /TEMP, TEMP=0.5
  __syncthreads();
  const int b = t >> 4;
  float m = -3.0e38f;
  for (int j = 0; j < 16; ++j) m = fmaxf(m, sl[b * 16 + j]);
  float sum = 0.f;
  for (int j = 0; j < 16; ++j) sum += expf(sl[b * 16 + j] - m);
  ws[WS_CP + t] = expf(sl[t] - m) / sum;
  if (t == 0) out[PQ_OFF] = prec_q(lpq);
}

// ---------------- K2: z2 (B*N) and b2 (K*S) ----------------
__global__ void __launch_bounds__(256) norms_kernel(
    const float* __restrict__ ze, const float* __restrict__ books,
    float* __restrict__ ws) {
  const int row = blockIdx.x * 4 + (threadIdx.x >> 6);
  const int lane = threadIdx.x & 63;
  const float* src = (row < (int)BN) ? (ze + (size_t)row * Dd)
                                     : (books + (size_t)(row - (int)BN) * Dd);
  float4 v = ((const float4*)src)[lane];
  float s = v.x * v.x + v.y * v.y + v.z * v.z + v.w * v.w;
#pragma unroll
  for (int d = 1; d < 64; d <<= 1) s += __shfl_xor(s, d);
  if (lane == 0) {
    if (row < (int)BN) ws[WS_Z2 + row] = s;
    else ws[WS_B2 + (row - (int)BN)] = s;
  }
}

// ---------------- K3: wbooks (B,S,D) and wb2 (B,S) ----------------
__global__ void __launch_bounds__(256) wbooks_kernel(
    const float* __restrict__ books, float* __restrict__ ws) {
  const int bs = blockIdx.x;           // b*512 + s
  const int b = bs >> 9, s = bs & 511;
  const int d = threadIdx.x;
  const float* cp = ws + WS_CP + b * 16;
  float acc = 0.f;
#pragma unroll
  for (int k = 0; k < 16; ++k)
    acc = fmaf(cp[k], books[((size_t)(k * Ss + s)) * Dd + d], acc);
  ws[WS_WBOOKS + ((size_t)(b * Ss + s)) * Dd + d] = acc;
  if (d == 0) {
    float a2 = 0.f;
#pragma unroll
    for (int k = 0; k < 16; ++k) a2 = fmaf(cp[k], ws[WS_B2 + k * Ss + s], a2);
    ws[WS_WB2 + b * Ss + s] = a2;
  }
}

// ---------------- K4: logits -> prob, log_prob ----------------
__global__ void __launch_bounds__(256, 4) logits_kernel(
    const float* __restrict__ ze, const float* __restrict__ lpq,
    const float* __restrict__ ws, float* __restrict__ out) {
  __shared__ float ze_s[8 * 256];
  __shared__ float ls[8 * 512];
  const int b = blockIdx.x >> 7;
  const int n0 = (blockIdx.x & 127) << 3;
  const int t = threadIdx.x;
  const float pq = prec_q(lpq);

  {
    const float4* zin = (const float4*)(ze + (size_t)(b * Nn + n0) * Dd);
    float4* zo = (float4*)ze_s;
    zo[t] = zin[t];
    zo[t + 256] = zin[t + 256];
  }
  __syncthreads();

  float acc0[8], acc1[8];
#pragma unroll
  for (int r = 0; r < 8; ++r) { acc0[r] = 0.f; acc1[r] = 0.f; }
  const int s0 = t, s1 = t + 256;
  const float4* w4_0 = (const float4*)(ws + WS_WBOOKS + (size_t)(b * Ss + s0) * Dd);
  const float4* w4_1 = (const float4*)(ws + WS_WBOOKS + (size_t)(b * Ss + s1) * Dd);
  const float4* z4 = (const float4*)ze_s;
  for (int dq = 0; dq < 64; ++dq) {
    float4 u0 = w4_0[dq], u1 = w4_1[dq];
#pragma unroll
    for (int r = 0; r < 8; ++r) {
      float4 z = z4[r * 64 + dq];
      acc0[r] = fmaf(z.x, u0.x, fmaf(z.y, u0.y, fmaf(z.z, u0.z, fmaf(z.w, u0.w, acc0[r]))));
      acc1[r] = fmaf(z.x, u1.x, fmaf(z.y, u1.y, fmaf(z.z, u1.z, fmaf(z.w, u1.w, acc1[r]))));
    }
  }
  const float wb2v0 = ws[WS_WB2 + b * Ss + s0];
  const float wb2v1 = ws[WS_WB2 + b * Ss + s1];
#pragma unroll
  for (int r = 0; r < 8; ++r) {
    float z2v = ws[WS_Z2 + b * Nn + n0 + r];
    ls[r * 512 + s0] = -pq * (z2v - 2.f * acc0[r] + wb2v0);
    ls[r * 512 + s1] = -pq * (z2v - 2.f * acc1[r] + wb2v1);
  }
  __syncthreads();

  const int r = t >> 5, c = t & 31;
  float m = -3.0e38f;
#pragma unroll
  for (int j = 0; j < 16; ++j) m = fmaxf(m, ls[r * 512 + c + 32 * j]);
#pragma unroll
  for (int d = 1; d < 32; d <<= 1) m = fmaxf(m, __shfl_xor(m, d));
  float ev[16];
  float sum = 0.f;
#pragma unroll
  for (int j = 0; j < 16; ++j) {
    ev[j] = expf(ls[r * 512 + c + 32 * j] - m);
    sum += ev[j];
  }
#pragma unroll
  for (int d = 1; d < 32; d <<= 1) sum += __shfl_xor(sum, d);
  const float inv = 1.f / sum;
  const float lsum = logf(sum);
  const size_t obase = (size_t)(b * Nn + n0 + r) * Ss;
  float* pr = out + PROB_OFF + obase;
  float* lp = out + LP_OFF + obase;
#pragma unroll
  for (int j = 0; j < 16; ++j) {
    int s = c + 32 * j;
    pr[s] = ev[j] * inv;
    lp[s] = (ls[r * 512 + s] - m) - lsum;
  }
}

// ---------------- K5: fused scores -> gumbel-softmax -> zq ----------------
__global__ void __launch_bounds__(256, 3) zq_kernel(
    const float* __restrict__ ze, const float* __restrict__ books,
    const float* __restrict__ lpq, const float* __restrict__ ws,
    float* __restrict__ out) {
  __shared__ float ze_s[16 * 256];   // 16 KB
  __shared__ float sc[16 * 512];     // 32 KB
  const int b = blockIdx.x >> 6;
  const int n0 = (blockIdx.x & 63) << 4;
  const int t = threadIdx.x;
  const float pq = prec_q(lpq);

  {
    const float4* zin = (const float4*)(ze + (size_t)(b * Nn + n0) * Dd);
    float4* zo = (float4*)ze_s;
#pragma unroll
    for (int i = 0; i < 4; ++i) zo[t + 256 * i] = zin[t + 256 * i];
  }
  __syncthreads();

  const int s0 = t, s1 = t + 256;
  const int rc = t >> 4, cc = t & 15;
  const float* cp = ws + WS_CP + b * 16;
  float zacc[16];
#pragma unroll
  for (int i = 0; i < 16; ++i) zacc[i] = 0.f;

  for (int k = 0; k < 16; ++k) {
    // ---- phase A: cross for columns s0,s1 over all 16 rows
    float acc0[16], acc1[16];
#pragma unroll
    for (int r2 = 0; r2 < 16; ++r2) { acc0[r2] = 0.f; acc1[r2] = 0.f; }
    const float4* b4_0 = (const float4*)(books + (size_t)(k * Ss + s0) * Dd);
    const float4* b4_1 = (const float4*)(books + (size_t)(k * Ss + s1) * Dd);
    const float4* z4 = (const float4*)ze_s;
    for (int dq = 0; dq < 64; ++dq) {
      float4 u0 = b4_0[dq], u1 = b4_1[dq];
#pragma unroll
      for (int r2 = 0; r2 < 16; ++r2) {
        float4 z = z4[r2 * 64 + dq];
        acc0[r2] = fmaf(z.x, u0.x, fmaf(z.y, u0.y, fmaf(z.z, u0.z, fmaf(z.w, u0.w, acc0[r2]))));
        acc1[r2] = fmaf(z.x, u1.x, fmaf(z.y, u1.y, fmaf(z.z, u1.z, fmaf(z.w, u1.w, acc1[r2]))));
      }
    }
    // scores + gumbel (z2 term cancels inside the per-k softmax)
    const float b2v0 = ws[WS_B2 + k * Ss + s0];
    const float b2v1 = ws[WS_B2 + k * Ss + s1];
#pragma unroll
    for (int r2 = 0; r2 < 16; ++r2) {
      uint32_t fl = ((uint32_t)(b * Nn + n0 + r2) * Kk + (uint32_t)k) * Ss + (uint32_t)s0;
      float g0 = jax_gumbel(KG2, fl, BNKS / 2u);
      float g1 = jax_gumbel(KG2, fl + 256u, BNKS / 2u);
      sc[r2 * 512 + s0] = ((2.f * acc0[r2] - b2v0) * pq + g0) * 2.0f;
      sc[r2 * 512 + s1] = ((2.f * acc1[r2] - b2v1) * pq + g1) * 2.0f;
    }
    __syncthreads();

    // ---- softmax over s within this k (row rc handled by 16 lanes)
    float m = -3.0e38f;
#pragma unroll
    for (int j = 0; j < 32; ++j) m = fmaxf(m, sc[rc * 512 + cc + 16 * j]);
#pragma unroll
    for (int d = 1; d < 16; d <<= 1) m = fmaxf(m, __shfl_xor(m, d));
    float sum = 0.f;
#pragma unroll
    for (int j = 0; j < 32; ++j) {
      int idx = rc * 512 + cc + 16 * j;
      float e = __expf(sc[idx] - m);
      sc[idx] = e;
      sum += e;
    }
#pragma unroll
    for (int d = 1; d < 16; d <<= 1) sum += __shfl_xor(sum, d);
    const float wmul = cp[k] / sum;
#pragma unroll
    for (int j = 0; j < 32; ++j) sc[rc * 512 + cc + 16 * j] *= wmul;
    // (no barrier: phase C reads only row rc, written by the same 16-lane group)

    // ---- phase C: zq accumulation, thread owns d = cc*16 .. cc*16+15 of row rc
    const float* bbase = books + (size_t)(k * Ss) * Dd + cc * 16;
    const float4* scrow = (const float4*)(sc + rc * 512);
    for (int s4 = 0; s4 < 128; ++s4) {
      float4 wv = scrow[s4];
      const float w4a[4] = {wv.x, wv.y, wv.z, wv.w};
#pragma unroll
      for (int e = 0; e < 4; ++e) {
        const float4* row = (const float4*)(bbase + (size_t)(s4 * 4 + e) * Dd);
        float w = w4a[e];
        float4 q0 = row[0], q1 = row[1], q2 = row[2], q3 = row[3];
        zacc[0]  = fmaf(w, q0.x, zacc[0]);
        zacc[1]  = fmaf(w, q0.y, zacc[1]);
        zacc[2]  = fmaf(w, q0.z, zacc[2]);
        zacc[3]  = fmaf(w, q0.w, zacc[3]);
        zacc[4]  = fmaf(w, q1.x, zacc[4]);
        zacc[5]  = fmaf(w, q1.y, zacc[5]);
        zacc[6]  = fmaf(w, q1.z, zacc[6]);
        zacc[7]  = fmaf(w, q1.w, zacc[7]);
        zacc[8]  = fmaf(w, q2.x, zacc[8]);
        zacc[9]  = fmaf(w, q2.y, zacc[9]);
        zacc[10] = fmaf(w, q2.z, zacc[10]);
        zacc[11] = fmaf(w, q2.w, zacc[11]);
        zacc[12] = fmaf(w, q3.x, zacc[12]);
        zacc[13] = fmaf(w, q3.y, zacc[13]);
        zacc[14] = fmaf(w, q3.z, zacc[14]);
        zacc[15] = fmaf(w, q3.w, zacc[15]);
      }
    }
    __syncthreads();  // protect sc before next k's phase A overwrites it
  }

  float4* o4 = (float4*)(out + (size_t)(b * Nn + n0 + rc) * Dd + cc * 16);
  o4[0] = make_float4(zacc[0], zacc[1], zacc[2], zacc[3]);
  o4[1] = make_float4(zacc[4], zacc[5], zacc[6], zacc[7]);
  o4[2] = make_float4(zacc[8], zacc[9], zacc[10], zacc[11]);
  o4[3] = make_float4(zacc[12], zacc[13], zacc[14], zacc[15]);
}

}  // namespace

extern "C" void kernel_launch(void* const* d_in, const int* in_sizes, int n_in,
                              void* d_out, int out_size, void* d_ws, size_t ws_size,
                              hipStream_t stream) {
  (void)in_sizes; (void)n_in; (void)out_size; (void)ws_size;
  const float* ze = (const float*)d_in[0];
  const float* c_logits = (const float*)d_in[1];
  const float* books = (const float*)d_in[2];
  const float* lpq = (const float*)d_in[3];
  const float* lpq_cls = (const float*)d_in[4];
  float* out = (float*)d_out;
  float* ws = (float*)d_ws;

  hipLaunchKernelGGL(cprobs_kernel, dim3(1), dim3(256), 0, stream,
                     c_logits, lpq, lpq_cls, ws, out);
  hipLaunchKernelGGL(norms_kernel, dim3((BN + Kk * Ss) / 4), dim3(256), 0, stream,
                     ze, books, ws);
  hipLaunchKernelGGL(wbooks_kernel, dim3(Bsz * Ss), dim3(256), 0, stream,
                     books, ws);
  hipLaunchKernelGGL(logits_kernel, dim3(Bsz * (Nn / 8)), dim3(256), 0, stream,
                     ze, lpq, ws, out);
  hipLaunchKernelGGL(zq_kernel, dim3(Bsz * (Nn / 16)), dim3(256), 0, stream,
                     ze, books, lpq, ws, out);
}

// Round 2
// 884.957 us; speedup vs baseline: 10.1804x; 10.1804x over previous
//
#include <hip/hip_runtime.h>
#include <cstdint>
#include <cstddef>

#define JAX_PARTITIONABLE 1

namespace {

constexpr int Bsz = 16, Nn = 1024, Dd = 256, Kk = 16, Ss = 512;
constexpr uint32_t BN = (uint32_t)Bsz * Nn;                    // 16384
constexpr int ZQ_SIZE = Bsz * Nn * Dd;                          // 4194304
constexpr int PQ_OFF = ZQ_SIZE;
constexpr int PROB_OFF = ZQ_SIZE + 1;
constexpr int BNS = Bsz * Nn * Ss;                              // 8388608
constexpr int LP_OFF = PROB_OFF + BNS;

// workspace layout (float offsets)
constexpr int WS_CP = 0;                           // 256
constexpr int WS_B2 = 256;                         // K*S = 8192
constexpr int WS_WB2 = WS_B2 + Kk * Ss;            // B*S = 8192
constexpr int WS_WBOOKS = WS_WB2 + Bsz * Ss;       // B*S*D = 2097152
constexpr int WS_BBF = WS_WBOOKS + Bsz * Ss * Dd;  // books bf16: 2M shorts = 1M floats
constexpr int WS_BTF = WS_BBF + (Kk * Ss * Dd) / 2; // bookT bf16 [k][d][s]
// total ~4.2M floats ~ 16.9 MB

typedef __attribute__((ext_vector_type(8))) short bf16x8;
typedef __attribute__((ext_vector_type(4))) short short4v;
typedef __attribute__((ext_vector_type(4))) float f32x4;

struct KP { uint32_t a, b; };

__host__ __device__ constexpr KP tf2x32(uint32_t k0, uint32_t k1,
                                        uint32_t x0, uint32_t x1) {
  uint32_t ks[3] = {k0, k1, k0 ^ k1 ^ 0x1BD11BDAu};
  const int rot[2][4] = {{13, 15, 26, 6}, {17, 29, 16, 24}};
  x0 += ks[0];
  x1 += ks[1];
#pragma unroll
  for (int i = 0; i < 5; ++i) {
#pragma unroll
    for (int j = 0; j < 4; ++j) {
      int r = rot[i & 1][j];
      x0 += x1;
      x1 = (x1 << r) | (x1 >> (32 - r));
      x1 ^= x0;
    }
    x0 += ks[(i + 1) % 3];
    x1 += ks[(i + 2) % 3] + (uint32_t)(i + 1);
  }
  return {x0, x1};
}

#if JAX_PARTITIONABLE
constexpr KP KG1 = tf2x32(0u, 42u, 0u, 0u);
constexpr KP KG2 = tf2x32(0u, 42u, 0u, 1u);
#else
constexpr KP KH0 = tf2x32(0u, 42u, 0u, 2u);
constexpr KP KH1 = tf2x32(0u, 42u, 1u, 3u);
constexpr KP KG1 = {KH0.a, KH1.a};
constexpr KP KG2 = {KH0.b, KH1.b};
#endif

__device__ __forceinline__ float jax_gumbel(KP key, uint32_t idx, uint32_t half) {
#if JAX_PARTITIONABLE
  (void)half;
  KP h = tf2x32(key.a, key.b, 0u, idx);
  uint32_t bits = h.a ^ h.b;
#else
  uint32_t lo = idx < half ? idx : idx - half;
  KP h = tf2x32(key.a, key.b, lo, lo + half);
  uint32_t bits = idx < half ? h.a : h.b;
#endif
  float u = __uint_as_float((bits >> 9) | 0x3F800000u) - 1.0f;
  return -__logf(-__logf(u + 1e-10f) + 1e-10f);
}

__device__ __forceinline__ float prec_q(const float* p) {
  return 0.5f / fmaxf(1.0f + expf(p[0]), 1e-10f);
}

__device__ __forceinline__ short f2bf(float x) {  // RNE f32->bf16
  uint32_t u = __float_as_uint(x);
  uint32_t r = (u + 0x7FFFu + ((u >> 16) & 1u)) >> 16;
  return (short)r;
}

// ---------------- K1: c_probs (B,K) + precision_q ----------------
__global__ void __launch_bounds__(256) cprobs_kernel(
    const float* __restrict__ c_logits, const float* __restrict__ lpq,
    const float* __restrict__ lpq_cls, float* __restrict__ ws,
    float* __restrict__ out) {
  __shared__ float sl[256];
  const int t = threadIdx.x;
  const float pqc = prec_q(lpq_cls);
  float g = jax_gumbel(KG1, (uint32_t)t, 128u);
  sl[t] = (c_logits[t] * pqc + g) * 2.0f;  // /TEMP, TEMP=0.5
  __syncthreads();
  const int b = t >> 4;
  float m = -3.0e38f;
  for (int j = 0; j < 16; ++j) m = fmaxf(m, sl[b * 16 + j]);
  float sum = 0.f;
  for (int j = 0; j < 16; ++j) sum += expf(sl[b * 16 + j] - m);
  ws[WS_CP + t] = expf(sl[t] - m) / sum;
  if (t == 0) out[PQ_OFF] = prec_q(lpq);
}

// ---------------- K2: b2 (K*S) ----------------
__global__ void __launch_bounds__(256) norms_kernel(
    const float* __restrict__ books, float* __restrict__ ws) {
  const int row = blockIdx.x * 4 + (threadIdx.x >> 6);
  const int lane = threadIdx.x & 63;
  float4 v = ((const float4*)(books + (size_t)row * Dd))[lane];
  float s = v.x * v.x + v.y * v.y + v.z * v.z + v.w * v.w;
#pragma unroll
  for (int d = 1; d < 64; d <<= 1) s += __shfl_xor(s, d);
  if (lane == 0) ws[WS_B2 + row] = s;
}

// ---------------- K3: books -> bf16 + transposed bf16 ----------------
__global__ void __launch_bounds__(256) prep_kernel(
    const float* __restrict__ books, float* __restrict__ ws) {
  __shared__ short tile[16 * 256];
  const int k = blockIdx.x >> 5;
  const int s0 = (blockIdx.x & 31) << 4;
  short* bbf = (short*)(ws + WS_BBF);
  short* btf = (short*)(ws + WS_BTF);
  const int t = threadIdx.x;
#pragma unroll
  for (int i = 0; i < 4; ++i) {
    int idx = t + 256 * i;  // 0..1023
    int r = idx >> 6, dq = idx & 63;
    float4 v = ((const float4*)books)[(size_t)(k * Ss + s0 + r) * 64 + dq];
    short4v h = {f2bf(v.x), f2bf(v.y), f2bf(v.z), f2bf(v.w)};
    *(short4v*)&bbf[(size_t)(k * Ss + s0 + r) * 256 + dq * 4] = h;
    *(short4v*)&tile[r * 256 + dq * 4] = h;
  }
  __syncthreads();
  const int d = t;  // 0..255
  short vals[16];
#pragma unroll
  for (int r = 0; r < 16; ++r) vals[r] = tile[r * 256 + d];
  bf16x8 lo, hi;
#pragma unroll
  for (int r = 0; r < 8; ++r) { lo[r] = vals[r]; hi[r] = vals[r + 8]; }
  size_t base = ((size_t)(k * 256 + d)) * 512 + s0;
  *(bf16x8*)&btf[base] = lo;
  *(bf16x8*)&btf[base + 8] = hi;
}

// ---------------- K4: wbooks (B,S,D) and wb2 (B,S) ----------------
__global__ void __launch_bounds__(256) wbooks_kernel(
    const float* __restrict__ books, float* __restrict__ ws) {
  const int bs = blockIdx.x;           // b*512 + s
  const int b = bs >> 9, s = bs & 511;
  const int d = threadIdx.x;
  const float* cp = ws + WS_CP + b * 16;
  float acc = 0.f;
#pragma unroll
  for (int k = 0; k < 16; ++k)
    acc = fmaf(cp[k], books[((size_t)(k * Ss + s)) * Dd + d], acc);
  ws[WS_WBOOKS + ((size_t)(b * Ss + s)) * Dd + d] = acc;
  if (d == 0) {
    float a2 = 0.f;
#pragma unroll
    for (int k = 0; k < 16; ++k) a2 = fmaf(cp[k], ws[WS_B2 + k * Ss + s], a2);
    ws[WS_WB2 + b * Ss + s] = a2;
  }
}

// ---------------- K5: logits -> prob, log_prob (z2 dropped: softmax-invariant) ----
__global__ void __launch_bounds__(256, 4) logits_kernel(
    const float* __restrict__ ze, const float* __restrict__ lpq,
    const float* __restrict__ ws, float* __restrict__ out) {
  __shared__ float ze_s[8 * 256];
  __shared__ float ls[8 * 512];
  const int b = blockIdx.x >> 7;
  const int n0 = (blockIdx.x & 127) << 3;
  const int t = threadIdx.x;
  const float pq = prec_q(lpq);

  {
    const float4* zin = (const float4*)(ze + (size_t)(b * Nn + n0) * Dd);
    float4* zo = (float4*)ze_s;
    zo[t] = zin[t];
    zo[t + 256] = zin[t + 256];
  }
  __syncthreads();

  float acc0[8], acc1[8];
#pragma unroll
  for (int r = 0; r < 8; ++r) { acc0[r] = 0.f; acc1[r] = 0.f; }
  const int s0 = t, s1 = t + 256;
  const float4* w4_0 = (const float4*)(ws + WS_WBOOKS + (size_t)(b * Ss + s0) * Dd);
  const float4* w4_1 = (const float4*)(ws + WS_WBOOKS + (size_t)(b * Ss + s1) * Dd);
  const float4* z4 = (const float4*)ze_s;
  for (int dq = 0; dq < 64; ++dq) {
    float4 u0 = w4_0[dq], u1 = w4_1[dq];
#pragma unroll
    for (int r = 0; r < 8; ++r) {
      float4 z = z4[r * 64 + dq];
      acc0[r] = fmaf(z.x, u0.x, fmaf(z.y, u0.y, fmaf(z.z, u0.z, fmaf(z.w, u0.w, acc0[r]))));
      acc1[r] = fmaf(z.x, u1.x, fmaf(z.y, u1.y, fmaf(z.z, u1.z, fmaf(z.w, u1.w, acc1[r]))));
    }
  }
  const float wb2v0 = ws[WS_WB2 + b * Ss + s0];
  const float wb2v1 = ws[WS_WB2 + b * Ss + s1];
#pragma unroll
  for (int r = 0; r < 8; ++r) {
    ls[r * 512 + s0] = pq * (2.f * acc0[r] - wb2v0);
    ls[r * 512 + s1] = pq * (2.f * acc1[r] - wb2v1);
  }
  __syncthreads();

  const int r = t >> 5, c = t & 31;
  float m = -3.0e38f;
#pragma unroll
  for (int j = 0; j < 16; ++j) m = fmaxf(m, ls[r * 512 + c + 32 * j]);
#pragma unroll
  for (int d = 1; d < 32; d <<= 1) m = fmaxf(m, __shfl_xor(m, d));
  float ev[16];
  float sum = 0.f;
#pragma unroll
  for (int j = 0; j < 16; ++j) {
    ev[j] = expf(ls[r * 512 + c + 32 * j] - m);
    sum += ev[j];
  }
#pragma unroll
  for (int d = 1; d < 32; d <<= 1) sum += __shfl_xor(sum, d);
  const float inv = 1.f / sum;
  const float lsum = logf(sum);
  const size_t obase = (size_t)(b * Nn + n0 + r) * Ss;
  float* pr = out + PROB_OFF + obase;
  float* lp = out + LP_OFF + obase;
#pragma unroll
  for (int j = 0; j < 16; ++j) {
    int s = c + 32 * j;
    pr[s] = ev[j] * inv;
    lp[s] = (ls[r * 512 + s] - m) - lsum;
  }
}

// ---------------- K6: fused MFMA zq ----------------
// block: 512 thr (8 waves), n-tile = 32 rows. Wave w: GEMM1 cols s in
// [w*64,w*64+64), GEMM2 d in [w*32,w*32+32). C-layout: col=lane&15,
// row=(lane>>4)*4+reg; A-frag: m=lane&15, k=(lane>>4)*8+j.
__global__ void __launch_bounds__(512, 4) zq_kernel(
    const float* __restrict__ ze, const float* __restrict__ lpq,
    const float* __restrict__ ws, float* __restrict__ out) {
  __shared__ short ze_s[32 * 264];   // bf16, row stride 264 (bank-balanced)
  __shared__ short enc_s[32 * 520];  // bf16, row stride 520
  __shared__ float redmax[8][32];
  __shared__ float redsum[8][32];
  __shared__ float finalM[32];
  __shared__ float finalT[32];       // 1/T
  __shared__ float cpk[16];

  const int b = blockIdx.x >> 5;
  const int n0 = (blockIdx.x & 31) << 5;
  const int t = threadIdx.x;
  const int w = t >> 6, lane = t & 63, c = lane & 15, q = lane >> 4;
  const float pq = prec_q(lpq);
  const short* bbf = (const short*)(ws + WS_BBF);
  const short* btf = (const short*)(ws + WS_BTF);
  const float* b2p = ws + WS_B2;

  if (t < 16) cpk[t] = ws[WS_CP + b * 16 + t];
#pragma unroll
  for (int i = 0; i < 4; ++i) {
    int idx = t + 512 * i;  // 0..2047
    int r = idx >> 6, dq = idx & 63;
    float4 v = ((const float4*)ze)[(size_t)(b * Nn + n0 + r) * 64 + dq];
    short4v h = {f2bf(v.x), f2bf(v.y), f2bf(v.z), f2bf(v.w)};
    *(short4v*)&ze_s[r * 264 + dq * 4] = h;
  }
  __syncthreads();

  f32x4 acc2[2][2];
#pragma unroll
  for (int rt = 0; rt < 2; ++rt)
#pragma unroll
    for (int dt = 0; dt < 2; ++dt) acc2[rt][dt] = (f32x4)(0.f);

  for (int k = 0; k < 16; ++k) {
    // ---- GEMM1: scores = ze . books[k]^T
    f32x4 acc1[2][4];
#pragma unroll
    for (int rt = 0; rt < 2; ++rt)
#pragma unroll
      for (int st = 0; st < 4; ++st) acc1[rt][st] = (f32x4)(0.f);
    for (int dstep = 0; dstep < 8; ++dstep) {
      bf16x8 a0 = *(const bf16x8*)&ze_s[(c) * 264 + dstep * 32 + q * 8];
      bf16x8 a1 = *(const bf16x8*)&ze_s[(16 + c) * 264 + dstep * 32 + q * 8];
#pragma unroll
      for (int st = 0; st < 4; ++st) {
        bf16x8 bB = *(const bf16x8*)&bbf[((size_t)(k * Ss + w * 64 + st * 16 + c)) * 256 +
                                         dstep * 32 + q * 8];
        acc1[0][st] = __builtin_amdgcn_mfma_f32_16x16x32_bf16(a0, bB, acc1[0][st], 0, 0, 0);
        acc1[1][st] = __builtin_amdgcn_mfma_f32_16x16x32_bf16(a1, bB, acc1[1][st], 0, 0, 0);
      }
    }

    // ---- scores + gumbel in C-layout registers
    float b2v[4];
#pragma unroll
    for (int st = 0; st < 4; ++st) b2v[st] = b2p[k * Ss + w * 64 + st * 16 + c];
    float mx[2][4], sm[2][4];
#pragma unroll
    for (int rt = 0; rt < 2; ++rt)
#pragma unroll
      for (int reg = 0; reg < 4; ++reg) mx[rt][reg] = -3.0e38f;
#pragma unroll
    for (int rt = 0; rt < 2; ++rt)
#pragma unroll
      for (int st = 0; st < 4; ++st)
#pragma unroll
        for (int reg = 0; reg < 4; ++reg) {
          int row = n0 + rt * 16 + q * 4 + reg;
          uint32_t gi = ((uint32_t)(b * Nn + row) * (uint32_t)Kk + (uint32_t)k) * (uint32_t)Ss +
                        (uint32_t)(w * 64 + st * 16 + c);
          float g = jax_gumbel(KG2, gi, 0u);
          float v = ((2.f * acc1[rt][st][reg] - b2v[st]) * pq + g) * 2.f;
          acc1[rt][st][reg] = v;
          mx[rt][reg] = fmaxf(mx[rt][reg], v);
        }
#pragma unroll
    for (int m = 1; m < 16; m <<= 1)
#pragma unroll
      for (int rt = 0; rt < 2; ++rt)
#pragma unroll
        for (int reg = 0; reg < 4; ++reg)
          mx[rt][reg] = fmaxf(mx[rt][reg], __shfl_xor(mx[rt][reg], m));
#pragma unroll
    for (int rt = 0; rt < 2; ++rt)
#pragma unroll
      for (int reg = 0; reg < 4; ++reg) sm[rt][reg] = 0.f;
#pragma unroll
    for (int rt = 0; rt < 2; ++rt)
#pragma unroll
      for (int st = 0; st < 4; ++st)
#pragma unroll
        for (int reg = 0; reg < 4; ++reg) {
          float e = __expf(acc1[rt][st][reg] - mx[rt][reg]);
          acc1[rt][st][reg] = e;
          sm[rt][reg] += e;
        }
#pragma unroll
    for (int m = 1; m < 16; m <<= 1)
#pragma unroll
      for (int rt = 0; rt < 2; ++rt)
#pragma unroll
        for (int reg = 0; reg < 4; ++reg) sm[rt][reg] += __shfl_xor(sm[rt][reg], m);
    if (c == 0) {
#pragma unroll
      for (int rt = 0; rt < 2; ++rt)
#pragma unroll
        for (int reg = 0; reg < 4; ++reg) {
          int rl = rt * 16 + q * 4 + reg;
          redmax[w][rl] = mx[rt][reg];
          redsum[w][rl] = sm[rt][reg];
        }
    }
    __syncthreads();
    if (t < 32) {
      float M = redmax[0][t];
#pragma unroll
      for (int w2 = 1; w2 < 8; ++w2) M = fmaxf(M, redmax[w2][t]);
      float T = 0.f;
#pragma unroll
      for (int w2 = 0; w2 < 8; ++w2) T += redsum[w2][t] * __expf(redmax[w2][t] - M);
      finalM[t] = M;
      finalT[t] = 1.f / T;
    }
    __syncthreads();

    // ---- enc = e * cp[k] * exp(mx - M) / T  -> bf16 LDS (A-layout source)
    const float cpv = cpk[k];
#pragma unroll
    for (int rt = 0; rt < 2; ++rt)
#pragma unroll
      for (int reg = 0; reg < 4; ++reg) {
        int rl = rt * 16 + q * 4 + reg;
        float scale = cpv * __expf(mx[rt][reg] - finalM[rl]) * finalT[rl];
#pragma unroll
        for (int st = 0; st < 4; ++st)
          enc_s[rl * 520 + w * 64 + st * 16 + c] = f2bf(acc1[rt][st][reg] * scale);
      }
    __syncthreads();

    // ---- GEMM2: zq += enc . bookT[k]
    for (int ss = 0; ss < 16; ++ss) {
      bf16x8 a0 = *(const bf16x8*)&enc_s[(c) * 520 + ss * 32 + q * 8];
      bf16x8 a1 = *(const bf16x8*)&enc_s[(16 + c) * 520 + ss * 32 + q * 8];
#pragma unroll
      for (int dt = 0; dt < 2; ++dt) {
        bf16x8 bB = *(const bf16x8*)&btf[((size_t)(k * 256 + w * 32 + dt * 16 + c)) * 512 +
                                         ss * 32 + q * 8];
        acc2[0][dt] = __builtin_amdgcn_mfma_f32_16x16x32_bf16(a0, bB, acc2[0][dt], 0, 0, 0);
        acc2[1][dt] = __builtin_amdgcn_mfma_f32_16x16x32_bf16(a1, bB, acc2[1][dt], 0, 0, 0);
      }
    }
    __syncthreads();  // protect enc_s before next k's writes
  }

  // ---- epilogue: C-layout -> global zq
#pragma unroll
  for (int rt = 0; rt < 2; ++rt)
#pragma unroll
    for (int dt = 0; dt < 2; ++dt)
#pragma unroll
      for (int reg = 0; reg < 4; ++reg) {
        int row = n0 + rt * 16 + q * 4 + reg;
        int d = w * 32 + dt * 16 + c;
        out[(size_t)(b * Nn + row) * Dd + d] = acc2[rt][dt][reg];
      }
}

}  // namespace

extern "C" void kernel_launch(void* const* d_in, const int* in_sizes, int n_in,
                              void* d_out, int out_size, void* d_ws, size_t ws_size,
                              hipStream_t stream) {
  (void)in_sizes; (void)n_in; (void)out_size; (void)ws_size;
  const float* ze = (const float*)d_in[0];
  const float* c_logits = (const float*)d_in[1];
  const float* books = (const float*)d_in[2];
  const float* lpq = (const float*)d_in[3];
  const float* lpq_cls = (const float*)d_in[4];
  float* out = (float*)d_out;
  float* ws = (float*)d_ws;

  hipLaunchKernelGGL(cprobs_kernel, dim3(1), dim3(256), 0, stream,
                     c_logits, lpq, lpq_cls, ws, out);
  hipLaunchKernelGGL(norms_kernel, dim3(Kk * Ss / 4), dim3(256), 0, stream, books, ws);
  hipLaunchKernelGGL(prep_kernel, dim3(Kk * 32), dim3(256), 0, stream, books, ws);
  hipLaunchKernelGGL(wbooks_kernel, dim3(Bsz * Ss), dim3(256), 0, stream, books, ws);
  hipLaunchKernelGGL(logits_kernel, dim3(Bsz * (Nn / 8)), dim3(256), 0, stream,
                     ze, lpq, ws, out);
  hipLaunchKernelGGL(zq_kernel, dim3(Bsz * (Nn / 32)), dim3(512), 0, stream,
                     ze, lpq, ws, out);
}